// Round 14
// baseline (61.675 us; speedup 1.0000x reference)
//
#include <hip/hip_runtime.h>
#include <hip/hip_bf16.h>
#include <math.h>

typedef __bf16 bf16x8 __attribute__((ext_vector_type(8)));
typedef float  f32x4  __attribute__((ext_vector_type(4)));

#define B_ 32
#define T_ 8192

// tanh via v_exp(exp2) + v_rcp; 2*log2(e) folded into one mul.
// rcpf R9/R10-proven; exp2 is the same v_exp_f32 instruction (D=2^S0).
__device__ __forceinline__ float tanh_fast(float x) {
  const float ex = __builtin_amdgcn_exp2f(x * 2.8853900817779268f);
  return 1.0f - 2.0f * __builtin_amdgcn_rcpf(ex + 1.0f);
}

// All-reduce (sum) over each 16-lane row via DPP row_ror (R11-proven).
template <int CTRL>
__device__ __forceinline__ float dpp_ror_add(float x) {
  const int y = __builtin_amdgcn_update_dpp(
      0, __builtin_bit_cast(int, x), CTRL, 0xF, 0xF, false);
  return x + __builtin_bit_cast(float, y);
}
__device__ __forceinline__ float allred16(float x) {
  x = dpp_ror_add<0x121>(x);   // row_ror:1
  x = dpp_ror_add<0x122>(x);   // row_ror:2
  x = dpp_ror_add<0x124>(x);   // row_ror:4
  x = dpp_ror_add<0x128>(x);   // row_ror:8
  return x;
}

// K0: blocks 0..15 compute add[b][a] = dec_feat + b_dec + b_enc + b_cov;
//     blocks 16..23 rearrange Wk into bf16 MFMA B-fragment order.
__global__ __launch_bounds__(256) void setup_kernel(
    const float* __restrict__ dec, const float* __restrict__ b_enc,
    const float* __restrict__ W_dec, const float* __restrict__ b_dec,
    const float* __restrict__ b_cov, const float* __restrict__ Wk,
    float* __restrict__ addbuf, __bf16* __restrict__ wfrag)
{
  const int blk = blockIdx.x, tid = threadIdx.x;
  if (blk < 16) {
    const int idx = blk * 256 + tid;          // [0, 4096)
    const int b = idx >> 7, a = idx & 127;
    float acc = b_dec[a] + b_enc[a] + b_cov[a];
    for (int k = 0; k < 128; ++k)
      acc += dec[b * 128 + k] * W_dec[k * 128 + a];
    addbuf[idx] = acc;
  } else {
    // fragment id f = (ct*4+ks)*64 + lane; element j: B[k][col]
    // k = ks*32 + (lane>>4)*8 + j, col = ct*16 + (lane&15)
    const int f = (blk - 16) * 256 + tid;     // [0, 2048)
    const int l = f & 63;
    const int rest = f >> 6;                  // ct*4 + ks
    const int ks = rest & 3, ct = rest >> 2;
    for (int j = 0; j < 8; ++j) {
      const int k = ks * 32 + (l >> 4) * 8 + j;
      const int a = ct * 16 + (l & 15);
      wfrag[f * 8 + j] = (__bf16)Wk[k * 128 + a];
    }
  }
}

// K1 (fused): R11 champion per-lane code; each block now processes TWO
// 128-row groups (grid 1024 = exactly 4 blocks/CU, all resident, one wfrag
// staging per 2 groups). Stats/pctx per 128-row group, same as champion.
__global__ __launch_bounds__(256, 4) void feat_ctx_kernel(
    const float* __restrict__ enc, const float* __restrict__ cov,
    const float* __restrict__ mask,
    const __bf16* __restrict__ wfrag_g, const float* __restrict__ addbuf,
    const float* __restrict__ Kc, const float* __restrict__ vvec,
    float* __restrict__ p_out, float* __restrict__ pctx,
    float* __restrict__ mblk, float* __restrict__ sblk)
{
  __shared__ __align__(16) float smem[8192];   // 32KB wfrag
  __shared__ float red[16];
  __shared__ float ctx_lds[4][128];
  const int tid  = threadIdx.x;
  const int lane = tid & 63;
  const int w    = tid >> 6;
  const int lr   = lane & 15;
  const int lg   = lane >> 4;
  const int b = (int)(blockIdx.x >> 5);        // 32 blocks per batch
  const long blockrow = (long)blockIdx.x * 256;

  // --- stage wfrag into LDS (32KB, coalesced) ---
  {
    const float4* src = (const float4*)wfrag_g;
    float4* dst = (float4*)smem;
#pragma unroll
    for (int i = 0; i < 8; ++i) dst[tid + i * 256] = src[tid + i * 256];
  }

  // --- group-0 A fragments issued pre-barrier (latency hides under it) ---
  bf16x8 afrag[2][4];
  long rowbase = blockrow + w * 32;
#pragma unroll
  for (int rt = 0; rt < 2; ++rt) {
    const float* rp = enc + (rowbase + rt * 16 + lr) * 128;
#pragma unroll
    for (int ks = 0; ks < 4; ++ks) {
      const float4 f0 = *(const float4*)(rp + ks * 32 + lg * 8);
      const float4 f1 = *(const float4*)(rp + ks * 32 + lg * 8 + 4);
      bf16x8 t;
      t[0]=(__bf16)f0.x; t[1]=(__bf16)f0.y; t[2]=(__bf16)f0.z; t[3]=(__bf16)f0.w;
      t[4]=(__bf16)f1.x; t[5]=(__bf16)f1.y; t[6]=(__bf16)f1.z; t[7]=(__bf16)f1.w;
      afrag[rt][ks] = t;
    }
  }

  // per-lane column constants (col = ct*16 + lr) — shared by both groups
  float addc[8], kcc[8], vc[8];
#pragma unroll
  for (int ct = 0; ct < 8; ++ct) {
    const int col = ct * 16 + lr;
    addc[ct] = addbuf[b * 128 + col];
    kcc[ct]  = Kc[col];
    vc[ct]   = vvec[col];
  }

  __syncthreads();   // wfrag staged
  const bf16x8* wf = (const bf16x8*)smem;

#pragma unroll 1
  for (int it = 0; it < 2; ++it) {
    rowbase = blockrow + it * 128 + w * 32;
    const int group = blockIdx.x * 2 + it;

    if (it > 0) {   // reload A fragments for group 1 (afrag dead by now)
#pragma unroll
      for (int rt = 0; rt < 2; ++rt) {
        const float* rp = enc + (rowbase + rt * 16 + lr) * 128;
#pragma unroll
        for (int ks = 0; ks < 4; ++ks) {
          const float4 f0 = *(const float4*)(rp + ks * 32 + lg * 8);
          const float4 f1 = *(const float4*)(rp + ks * 32 + lg * 8 + 4);
          bf16x8 t;
          t[0]=(__bf16)f0.x; t[1]=(__bf16)f0.y; t[2]=(__bf16)f0.z; t[3]=(__bf16)f0.w;
          t[4]=(__bf16)f1.x; t[5]=(__bf16)f1.y; t[6]=(__bf16)f1.z; t[7]=(__bf16)f1.w;
          afrag[rt][ks] = t;
        }
      }
    }
    const float4 cvA = *(const float4*)(cov + rowbase + lg * 4);
    const float4 cvB = *(const float4*)(cov + rowbase + 16 + lg * 4);
    const float cv8[2][4] = {{cvA.x, cvA.y, cvA.z, cvA.w},
                             {cvB.x, cvB.y, cvB.z, cvB.w}};

    // --- ct-outer MFMA + fused tanh epilogue ---
    float pacc[2][4];
#pragma unroll
    for (int rt = 0; rt < 2; ++rt)
#pragma unroll
      for (int q = 0; q < 4; ++q) pacc[rt][q] = 0.f;

#pragma unroll
    for (int ct = 0; ct < 8; ++ct) {
      bf16x8 bfr[4];
#pragma unroll
      for (int ks = 0; ks < 4; ++ks) bfr[ks] = wf[(ct * 4 + ks) * 64 + lane];
      f32x4 a0 = {0.f, 0.f, 0.f, 0.f};
      f32x4 a1 = {0.f, 0.f, 0.f, 0.f};
#pragma unroll
      for (int ks = 0; ks < 4; ++ks) {
        a0 = __builtin_amdgcn_mfma_f32_16x16x32_bf16(afrag[0][ks], bfr[ks], a0, 0, 0, 0);
        a1 = __builtin_amdgcn_mfma_f32_16x16x32_bf16(afrag[1][ks], bfr[ks], a1, 0, 0, 0);
      }
#pragma unroll
      for (int q = 0; q < 4; ++q) {
        const float x0 = a0[q] + addc[ct] + cv8[0][q] * kcc[ct];
        const float x1 = a1[q] + addc[ct] + cv8[1][q] * kcc[ct];
        pacc[0][q] += tanh_fast(x0) * vc[ct];
        pacc[1][q] += tanh_fast(x1) * vc[ct];
      }
    }

    // --- e: DPP all-reduce over the 16 lr lanes; row = rt*16 + lg*4 + q ---
    float e8[2][4];
#pragma unroll
    for (int rt = 0; rt < 2; ++rt)
#pragma unroll
      for (int q = 0; q < 4; ++q) e8[rt][q] = allred16(pacc[rt][q]);

    // wave max over its 32 rows, then block max
    float wm = e8[0][0];
#pragma unroll
    for (int rt = 0; rt < 2; ++rt)
#pragma unroll
      for (int q = 0; q < 4; ++q) wm = fmaxf(wm, e8[rt][q]);
    wm = fmaxf(wm, __shfl_xor(wm, 16));
    wm = fmaxf(wm, __shfl_xor(wm, 32));

    if (lane == 0) red[w] = wm;
    __syncthreads();
    const float m_loc = fmaxf(fmaxf(red[0], red[1]), fmaxf(red[2], red[3]));

    // p = exp(e - m_loc)*mask; block sum (cross-lg dedup only)
    const float4 mkA = *(const float4*)(mask + rowbase + lg * 4);
    const float4 mkB = *(const float4*)(mask + rowbase + 16 + lg * 4);
    const float mk8[2][4] = {{mkA.x, mkA.y, mkA.z, mkA.w},
                             {mkB.x, mkB.y, mkB.z, mkB.w}};
    float p8[2][4];
    float ps = 0.f;
#pragma unroll
    for (int rt = 0; rt < 2; ++rt)
#pragma unroll
      for (int q = 0; q < 4; ++q) {
        const float pv = __expf(e8[rt][q] - m_loc) * mk8[rt][q];
        p8[rt][q] = pv; ps += pv;
      }
    ps += __shfl_xor(ps, 16);
    ps += __shfl_xor(ps, 32);
    if (lane == 0) red[8 + w] = ps;

    // p for this lane's A-rows (rt*16 + lr): select on source lane + shfl
    float prow[2];
#pragma unroll
    for (int rt = 0; rt < 2; ++rt) {
      const int r3 = lr & 3;
      float sel = p8[rt][0];
      sel = (r3 == 1) ? p8[rt][1] : sel;
      sel = (r3 == 2) ? p8[rt][2] : sel;
      sel = (r3 == 3) ? p8[rt][3] : sel;
      prow[rt] = __shfl(sel, ((lr >> 2) << 4) | lr);
    }
    if (lg < 2) p_out[rowbase + lg * 16 + lr] = (lg == 0) ? prow[0] : prow[1];

    // --- partial context from register-held enc fragments ---
    float ctxp[32];
#pragma unroll
    for (int c = 0; c < 32; ++c) ctxp[c] = 0.f;
#pragma unroll
    for (int rt = 0; rt < 2; ++rt) {
      const float pr = prow[rt];
#pragma unroll
      for (int ks = 0; ks < 4; ++ks)
#pragma unroll
        for (int j = 0; j < 8; ++j)
          ctxp[ks * 8 + j] += pr * (float)afrag[rt][ks][j];
    }
    // reduce over the 16 lr lanes (rows) on the VALU (DPP), no DS ops
#pragma unroll
    for (int c = 0; c < 32; ++c) ctxp[c] = allred16(ctxp[c]);

    if (lr == 0) {
#pragma unroll
      for (int ks = 0; ks < 4; ++ks)
#pragma unroll
        for (int j = 0; j < 8; ++j)
          ctx_lds[w][ks * 32 + lg * 8 + j] = ctxp[ks * 8 + j];
    }
    __syncthreads();
    if (tid < 128) {
      const float s = ctx_lds[0][tid] + ctx_lds[1][tid] +
                      ctx_lds[2][tid] + ctx_lds[3][tid];
      pctx[(long)group * 128 + tid] = s;
    }
    if (tid == 0) {
      sblk[group] = red[8] + red[9] + red[10] + red[11];
      mblk[group] = m_loc;
    }
  }
}

// K2: per-batch combine of 64 group-partials -> ctx, alpha table.
__global__ __launch_bounds__(1024) void reduce_kernel(
    const float* __restrict__ mblk, const float* __restrict__ sblk,
    const float* __restrict__ pctx, float* __restrict__ alpha,
    float* __restrict__ ctx)
{
  const int b = blockIdx.x, tid = threadIdx.x;
  __shared__ float al[64];
  __shared__ float part[8][128];
  if (tid < 64) {
    const float mi = mblk[b * 64 + tid];
    const float si = sblk[b * 64 + tid];
    float m = mi;
#pragma unroll
    for (int off = 32; off > 0; off >>= 1) m = fmaxf(m, __shfl_xor(m, off));
    const float a = __expf(mi - m);
    float z = si * a;
#pragma unroll
    for (int off = 32; off > 0; off >>= 1) z += __shfl_xor(z, off);
    const float ai = a / z;
    al[tid] = ai;
    alpha[b * 64 + tid] = ai;
  }
  __syncthreads();
  const int v = tid & 127, ch = tid >> 7;
  float acc = 0.f;
#pragma unroll
  for (int k = 0; k < 8; ++k) {
    const int i = ch * 8 + k;
    acc += pctx[(long)(b * 64 + i) * 128 + v] * al[i];
  }
  part[ch][v] = acc;
  __syncthreads();
  if (tid < 128) {
    float s = 0.f;
#pragma unroll
    for (int c = 0; c < 8; ++c) s += part[c][tid];
    ctx[b * 128 + tid] = s;
  }
}

// K3: attn = p * alpha[128-row group]; covout = cov + attn.
__global__ __launch_bounds__(256) void finish_kernel(
    const float* __restrict__ p_buf, const float* __restrict__ alpha,
    const float* __restrict__ cov, float* __restrict__ attn,
    float* __restrict__ covout)
{
  const long idx = (long)blockIdx.x * 256 + threadIdx.x;   // [0, 262144)
  const float a = p_buf[idx] * alpha[idx >> 7];
  attn[idx] = a;
  covout[idx] = cov[idx] + a;
}

extern "C" void kernel_launch(void* const* d_in, const int* in_sizes, int n_in,
                              void* d_out, int out_size, void* d_ws, size_t ws_size,
                              hipStream_t stream) {
  const float* enc   = (const float*)d_in[0];
  const float* dec   = (const float*)d_in[1];
  const float* mask  = (const float*)d_in[2];
  const float* cov   = (const float*)d_in[3];
  const float* Wk    = (const float*)d_in[4];
  const float* b_enc = (const float*)d_in[5];
  const float* W_dec = (const float*)d_in[6];
  const float* b_dec = (const float*)d_in[7];
  const float* Kc    = (const float*)d_in[8];
  const float* b_cov = (const float*)d_in[9];
  const float* vvec  = (const float*)d_in[10];

  float* out    = (float*)d_out;
  float* ctx    = out;                  // B*A      = 4096
  float* attn   = out + B_ * 128;       // B*T      = 262144
  float* covout = attn + B_ * T_;       // B*T      = 262144

  char* ws = (char*)d_ws;
  __bf16* wfrag  = (__bf16*)ws;                          // 32 KB
  float*  addbuf = (float*)(ws + 32768);                 // 16 KB
  float*  p_buf  = (float*)(ws + 49152);                 // 1 MB
  float*  pctx   = (float*)(ws + 49152 + 1048576);       // 1 MB
  float*  mblk   = (float*)(ws + 49152 + 2097152);       // 8 KB
  float*  sblk   = (float*)(ws + 49152 + 2105344);       // 8 KB
  float*  alpha  = (float*)(ws + 49152 + 2113536);       // 8 KB

  setup_kernel   <<<24,   256, 0, stream>>>(dec, b_enc, W_dec, b_dec, b_cov, Wk,
                                            addbuf, wfrag);
  feat_ctx_kernel<<<1024, 256, 0, stream>>>(enc, cov, mask, wfrag, addbuf, Kc, vvec,
                                            p_buf, pctx, mblk, sblk);
  reduce_kernel  <<<32,  1024, 0, stream>>>(mblk, sblk, pctx, alpha, ctx);
  finish_kernel  <<<1024, 256, 0, stream>>>(p_buf, alpha, cov, attn, covout);
}

// Round 15
// 47.575 us; speedup vs baseline: 1.2964x; 1.2964x over previous
//
#include <hip/hip_runtime.h>
#include <hip/hip_bf16.h>
#include <math.h>

typedef __bf16 bf16x8 __attribute__((ext_vector_type(8)));
typedef float  f32x4  __attribute__((ext_vector_type(4)));

#define B_ 32
#define T_ 8192

// tanh via v_exp(2^x form) + v_rcp. rcpf R9/R10-proven; exp2 numerics
// R14-validated (absmax unchanged 0.0234). One v_mul saved vs __expf(2x).
__device__ __forceinline__ float tanh_fast(float x) {
  const float ex = __builtin_amdgcn_exp2f(x * 2.8853900817779268f);
  return 1.0f - 2.0f * __builtin_amdgcn_rcpf(ex + 1.0f);
}

// All-reduce (sum) over each 16-lane row via DPP row_ror (R11-proven).
template <int CTRL>
__device__ __forceinline__ float dpp_ror_add(float x) {
  const int y = __builtin_amdgcn_update_dpp(
      0, __builtin_bit_cast(int, x), CTRL, 0xF, 0xF, false);
  return x + __builtin_bit_cast(float, y);
}
__device__ __forceinline__ float allred16(float x) {
  x = dpp_ror_add<0x121>(x);   // row_ror:1
  x = dpp_ror_add<0x122>(x);   // row_ror:2
  x = dpp_ror_add<0x124>(x);   // row_ror:4
  x = dpp_ror_add<0x128>(x);   // row_ror:8
  return x;
}

// K0: blocks 0..15 compute add[b][a] = dec_feat + b_dec + b_enc + b_cov;
//     blocks 16..23 rearrange Wk into bf16 MFMA B-fragment order.
__global__ __launch_bounds__(256) void setup_kernel(
    const float* __restrict__ dec, const float* __restrict__ b_enc,
    const float* __restrict__ W_dec, const float* __restrict__ b_dec,
    const float* __restrict__ b_cov, const float* __restrict__ Wk,
    float* __restrict__ addbuf, __bf16* __restrict__ wfrag)
{
  const int blk = blockIdx.x, tid = threadIdx.x;
  if (blk < 16) {
    const int idx = blk * 256 + tid;          // [0, 4096)
    const int b = idx >> 7, a = idx & 127;
    float acc = b_dec[a] + b_enc[a] + b_cov[a];
    for (int k = 0; k < 128; ++k)
      acc += dec[b * 128 + k] * W_dec[k * 128 + a];
    addbuf[idx] = acc;
  } else {
    // fragment id f = (ct*4+ks)*64 + lane; element j: B[k][col]
    // k = ks*32 + (lane>>4)*8 + j, col = ct*16 + (lane&15)
    const int f = (blk - 16) * 256 + tid;     // [0, 2048)
    const int l = f & 63;
    const int rest = f >> 6;                  // ct*4 + ks
    const int ks = rest & 3, ct = rest >> 2;
    for (int j = 0; j < 8; ++j) {
      const int k = ks * 32 + (l >> 4) * 8 + j;
      const int a = ct * 16 + (l & 15);
      wfrag[f * 8 + j] = (__bf16)Wk[k * 128 + a];
    }
  }
}

// K1 (fused): R11 champion — LDS wfrag staging, 4-wave/128-row block,
// block softmax, DPP reduces, rcpf/exp2 tanh, float4 cov/mask loads.
__global__ __launch_bounds__(256, 4) void feat_ctx_kernel(
    const float* __restrict__ enc, const float* __restrict__ cov,
    const float* __restrict__ mask,
    const __bf16* __restrict__ wfrag_g, const float* __restrict__ addbuf,
    const float* __restrict__ Kc, const float* __restrict__ vvec,
    float* __restrict__ p_out, float* __restrict__ pctx,
    float* __restrict__ mblk, float* __restrict__ sblk)
{
  __shared__ __align__(16) float smem[8192];   // 32KB wfrag
  __shared__ float red[16];
  __shared__ float ctx_lds[4][128];
  const int tid  = threadIdx.x;
  const int lane = tid & 63;
  const int w    = tid >> 6;
  const int lr   = lane & 15;
  const int lg   = lane >> 4;
  const long rowbase = (long)blockIdx.x * 128 + w * 32;
  const int b = (int)(rowbase >> 13);

  // --- stage wfrag into LDS (32KB, coalesced) ---
  {
    const float4* src = (const float4*)wfrag_g;
    float4* dst = (float4*)smem;
#pragma unroll
    for (int i = 0; i < 8; ++i) dst[tid + i * 256] = src[tid + i * 256];
  }

  // --- A fragments: A[row = rowbase+rt*16+lr][k = ks*32 + lg*8 + j] ---
  bf16x8 afrag[2][4];
#pragma unroll
  for (int rt = 0; rt < 2; ++rt) {
    const float* rp = enc + (rowbase + rt * 16 + lr) * 128;
#pragma unroll
    for (int ks = 0; ks < 4; ++ks) {
      const float4 f0 = *(const float4*)(rp + ks * 32 + lg * 8);
      const float4 f1 = *(const float4*)(rp + ks * 32 + lg * 8 + 4);
      bf16x8 t;
      t[0]=(__bf16)f0.x; t[1]=(__bf16)f0.y; t[2]=(__bf16)f0.z; t[3]=(__bf16)f0.w;
      t[4]=(__bf16)f1.x; t[5]=(__bf16)f1.y; t[6]=(__bf16)f1.z; t[7]=(__bf16)f1.w;
      afrag[rt][ks] = t;
    }
  }

  // per-lane column constants (col = ct*16 + lr), per-row cov/mask (float4)
  float addc[8], kcc[8], vc[8];
#pragma unroll
  for (int ct = 0; ct < 8; ++ct) {
    const int col = ct * 16 + lr;
    addc[ct] = addbuf[b * 128 + col];
    kcc[ct]  = Kc[col];
    vc[ct]   = vvec[col];
  }
  const float4 cvA = *(const float4*)(cov + rowbase + lg * 4);
  const float4 cvB = *(const float4*)(cov + rowbase + 16 + lg * 4);
  float cv8[2][4] = {{cvA.x, cvA.y, cvA.z, cvA.w}, {cvB.x, cvB.y, cvB.z, cvB.w}};

  __syncthreads();   // wfrag staged

  // --- ct-outer MFMA + fused tanh epilogue ---
  float pacc[2][4];
#pragma unroll
  for (int rt = 0; rt < 2; ++rt)
#pragma unroll
    for (int q = 0; q < 4; ++q) pacc[rt][q] = 0.f;

  const bf16x8* wf = (const bf16x8*)smem;
#pragma unroll
  for (int ct = 0; ct < 8; ++ct) {
    bf16x8 bfr[4];
#pragma unroll
    for (int ks = 0; ks < 4; ++ks) bfr[ks] = wf[(ct * 4 + ks) * 64 + lane];
    f32x4 a0 = {0.f, 0.f, 0.f, 0.f};
    f32x4 a1 = {0.f, 0.f, 0.f, 0.f};
#pragma unroll
    for (int ks = 0; ks < 4; ++ks) {
      a0 = __builtin_amdgcn_mfma_f32_16x16x32_bf16(afrag[0][ks], bfr[ks], a0, 0, 0, 0);
      a1 = __builtin_amdgcn_mfma_f32_16x16x32_bf16(afrag[1][ks], bfr[ks], a1, 0, 0, 0);
    }
#pragma unroll
    for (int q = 0; q < 4; ++q) {
      const float x0 = a0[q] + addc[ct] + cv8[0][q] * kcc[ct];
      const float x1 = a1[q] + addc[ct] + cv8[1][q] * kcc[ct];
      pacc[0][q] += tanh_fast(x0) * vc[ct];
      pacc[1][q] += tanh_fast(x1) * vc[ct];
    }
  }

  // --- e: DPP all-reduce over the 16 lr lanes; row = rt*16 + lg*4 + q ---
  float e8[2][4];
#pragma unroll
  for (int rt = 0; rt < 2; ++rt)
#pragma unroll
    for (int q = 0; q < 4; ++q) e8[rt][q] = allred16(pacc[rt][q]);

  // wave max over its 32 rows, then block max
  float wm = e8[0][0];
#pragma unroll
  for (int rt = 0; rt < 2; ++rt)
#pragma unroll
    for (int q = 0; q < 4; ++q) wm = fmaxf(wm, e8[rt][q]);
  wm = fmaxf(wm, __shfl_xor(wm, 16));
  wm = fmaxf(wm, __shfl_xor(wm, 32));

  if (lane == 0) red[w] = wm;
  __syncthreads();
  const float m_loc = fmaxf(fmaxf(red[0], red[1]), fmaxf(red[2], red[3]));

  // p = exp(e - m_loc)*mask; block sum (cross-lg dedup only)
  const float4 mkA = *(const float4*)(mask + rowbase + lg * 4);
  const float4 mkB = *(const float4*)(mask + rowbase + 16 + lg * 4);
  const float mk8[2][4] = {{mkA.x, mkA.y, mkA.z, mkA.w},
                           {mkB.x, mkB.y, mkB.z, mkB.w}};
  float p8[2][4];
  float ps = 0.f;
#pragma unroll
  for (int rt = 0; rt < 2; ++rt)
#pragma unroll
    for (int q = 0; q < 4; ++q) {
      const float pv = __expf(e8[rt][q] - m_loc) * mk8[rt][q];
      p8[rt][q] = pv; ps += pv;
    }
  ps += __shfl_xor(ps, 16);
  ps += __shfl_xor(ps, 32);
  if (lane == 0) red[8 + w] = ps;

  // p for this lane's A-rows (rt*16 + lr): select on source lane + shfl
  float prow[2];
#pragma unroll
  for (int rt = 0; rt < 2; ++rt) {
    const int r3 = lr & 3;
    float sel = p8[rt][0];
    sel = (r3 == 1) ? p8[rt][1] : sel;
    sel = (r3 == 2) ? p8[rt][2] : sel;
    sel = (r3 == 3) ? p8[rt][3] : sel;
    prow[rt] = __shfl(sel, ((lr >> 2) << 4) | lr);
  }
  if (lg < 2) p_out[rowbase + lg * 16 + lr] = (lg == 0) ? prow[0] : prow[1];

  // --- partial context from register-held enc fragments ---
  float ctxp[32];
#pragma unroll
  for (int c = 0; c < 32; ++c) ctxp[c] = 0.f;
#pragma unroll
  for (int rt = 0; rt < 2; ++rt) {
    const float pr = prow[rt];
#pragma unroll
    for (int ks = 0; ks < 4; ++ks)
#pragma unroll
      for (int j = 0; j < 8; ++j)
        ctxp[ks * 8 + j] += pr * (float)afrag[rt][ks][j];
  }
  // reduce over the 16 lr lanes (rows) on the VALU (DPP), no DS ops
#pragma unroll
  for (int c = 0; c < 32; ++c) ctxp[c] = allred16(ctxp[c]);

  if (lr == 0) {
#pragma unroll
    for (int ks = 0; ks < 4; ++ks)
#pragma unroll
      for (int j = 0; j < 8; ++j)
        ctx_lds[w][ks * 32 + lg * 8 + j] = ctxp[ks * 8 + j];
  }
  __syncthreads();
  if (tid < 128) {
    const float s = ctx_lds[0][tid] + ctx_lds[1][tid] +
                    ctx_lds[2][tid] + ctx_lds[3][tid];
    pctx[(long)blockIdx.x * 128 + tid] = s;
  }
  if (tid == 0) {
    sblk[blockIdx.x] = red[8] + red[9] + red[10] + red[11];
    mblk[blockIdx.x] = m_loc;
  }
}

// K2: per-batch combine of 64 block-partials -> ctx, alpha table.
__global__ __launch_bounds__(1024) void reduce_kernel(
    const float* __restrict__ mblk, const float* __restrict__ sblk,
    const float* __restrict__ pctx, float* __restrict__ alpha,
    float* __restrict__ ctx)
{
  const int b = blockIdx.x, tid = threadIdx.x;
  __shared__ float al[64];
  __shared__ float part[8][128];
  if (tid < 64) {
    const float mi = mblk[b * 64 + tid];
    const float si = sblk[b * 64 + tid];
    float m = mi;
#pragma unroll
    for (int off = 32; off > 0; off >>= 1) m = fmaxf(m, __shfl_xor(m, off));
    const float a = __expf(mi - m);
    float z = si * a;
#pragma unroll
    for (int off = 32; off > 0; off >>= 1) z += __shfl_xor(z, off);
    const float ai = a / z;
    al[tid] = ai;
    alpha[b * 64 + tid] = ai;
  }
  __syncthreads();
  const int v = tid & 127, ch = tid >> 7;
  float acc = 0.f;
#pragma unroll
  for (int k = 0; k < 8; ++k) {
    const int i = ch * 8 + k;
    acc += pctx[(long)(b * 64 + i) * 128 + v] * al[i];
  }
  part[ch][v] = acc;
  __syncthreads();
  if (tid < 128) {
    float s = 0.f;
#pragma unroll
    for (int c = 0; c < 8; ++c) s += part[c][tid];
    ctx[b * 128 + tid] = s;
  }
}

// K3: attn = p * alpha[128-row block]; covout = cov + attn.
__global__ __launch_bounds__(256) void finish_kernel(
    const float* __restrict__ p_buf, const float* __restrict__ alpha,
    const float* __restrict__ cov, float* __restrict__ attn,
    float* __restrict__ covout)
{
  const long idx = (long)blockIdx.x * 256 + threadIdx.x;   // [0, 262144)
  const float a = p_buf[idx] * alpha[idx >> 7];
  attn[idx] = a;
  covout[idx] = cov[idx] + a;
}

extern "C" void kernel_launch(void* const* d_in, const int* in_sizes, int n_in,
                              void* d_out, int out_size, void* d_ws, size_t ws_size,
                              hipStream_t stream) {
  const float* enc   = (const float*)d_in[0];
  const float* dec   = (const float*)d_in[1];
  const float* mask  = (const float*)d_in[2];
  const float* cov   = (const float*)d_in[3];
  const float* Wk    = (const float*)d_in[4];
  const float* b_enc = (const float*)d_in[5];
  const float* W_dec = (const float*)d_in[6];
  const float* b_dec = (const float*)d_in[7];
  const float* Kc    = (const float*)d_in[8];
  const float* b_cov = (const float*)d_in[9];
  const float* vvec  = (const float*)d_in[10];

  float* out    = (float*)d_out;
  float* ctx    = out;                  // B*A      = 4096
  float* attn   = out + B_ * 128;       // B*T      = 262144
  float* covout = attn + B_ * T_;       // B*T      = 262144

  char* ws = (char*)d_ws;
  __bf16* wfrag  = (__bf16*)ws;                          // 32 KB
  float*  addbuf = (float*)(ws + 32768);                 // 16 KB
  float*  p_buf  = (float*)(ws + 49152);                 // 1 MB
  float*  pctx   = (float*)(ws + 49152 + 1048576);       // 1 MB
  float*  mblk   = (float*)(ws + 49152 + 2097152);       // 8 KB
  float*  sblk   = (float*)(ws + 49152 + 2105344);       // 8 KB
  float*  alpha  = (float*)(ws + 49152 + 2113536);       // 8 KB

  setup_kernel   <<<24,   256, 0, stream>>>(dec, b_enc, W_dec, b_dec, b_cov, Wk,
                                            addbuf, wfrag);
  feat_ctx_kernel<<<2048, 256, 0, stream>>>(enc, cov, mask, wfrag, addbuf, Kc, vvec,
                                            p_buf, pctx, mblk, sblk);
  reduce_kernel  <<<32,  1024, 0, stream>>>(mblk, sblk, pctx, alpha, ctx);
  finish_kernel  <<<1024, 256, 0, stream>>>(p_buf, alpha, cov, attn, covout);
}